// Round 1
// baseline (3244.173 us; speedup 1.0000x reference)
//
#include <hip/hip_runtime.h>
#include <cstdint>

// Cortex reservoir: embed(perm-gather) -> single-XCD persistent wave-autonomous
// spiking scan -> chunked dense readout GEMM.
//
// Scan coherence design (gfx950, 8 XCDs): 64 worker blocks confined to XCD 0
// (HW_REG_XCC_ID + ticket). Within one XCD the L2 is the coherence point:
//   release = s_waitcnt vmcnt(0) (stores reach write-through L2), plain flag store
//   acquire = agent-scope (sc0) flag load in the poll loop + one buffer_inv
// NEW this round: one wave owns one ROW (lane = 4 cols, float4), per-ROW flags,
// zero __syncthreads in the step loop (poll set == read-dependency set
// {0,±1,±2,±4,±6,±8}), S halo read straight from L2 (no LDS staging), and the
// horizontal pass does 6 b128 LDS reads instead of 56 b32 — the LDS pipe was
// the bottleneck (VALUBusy 2.2%, HBM 1.9%, ~4400 LDS cy/step/CU).
//
// ws layout (~72.8 MiB):
//   OFF_PERM  : perm int[1024]
//   OFF_FLAG  : row flags int[256*4] (16B padded) + ticket at [1024]
//   OFF_VSAVE : V snapshot float[65536]
//   OFF_S     : S ping-pong float[2][65536]
//   OFF_A     : A chunk float[128][131072]
//   OFF_P     : split-K partials float[128][128][128]

namespace {

constexpr int TT = 512;
constexpr int DD = 256;
constexpr int CELLS = DD * DD;              // 65536
constexpr long KTOT = 2L * CELLS;           // 131072
constexpr int TB = 128;                     // time-chunk
constexpr int NCH = TT / TB;                // 4
constexpr int KSLAB = 1024;
constexpr int NSLAB = 128;                  // KTOT / KSLAB
constexpr int NW = 64;                      // worker blocks (one XCD)

constexpr long OFF_PERM = 0;
constexpr long OFF_FLAG = 4096;
constexpr long OFF_VSAVE = OFF_FLAG + 8192;
constexpr long OFF_S = OFF_VSAVE + (long)CELLS * 4;
constexpr long OFF_A = OFF_S + 2L * CELLS * 4;
constexpr long OFF_P = OFF_A + (long)TB * KTOT * 4;
constexpr long WS_REQUIRED = OFF_P + (long)NSLAB * TB * 128 * 4;  // ~72.8 MiB

__device__ __forceinline__ int xcc_id() {
    int x;
    asm volatile("s_getreg_b32 %0, hwreg(HW_REG_XCC_ID, 0, 4)" : "=s"(x));
    return x;
}

__device__ __forceinline__ float4 f4add(float4 a, float4 b) {
    return make_float4(a.x + b.x, a.y + b.y, a.z + b.z, a.w + b.w);
}

__global__ __launch_bounds__(256) void perm_kernel(const float* __restrict__ We,
                                                   int* __restrict__ perm) {
    int idx = blockIdx.x * 256 + threadIdx.x;       // over 1024*1024
    if (We[idx] > 0.5f) perm[idx >> 10] = idx & 1023;
}

__global__ void ctrl_init(int* __restrict__ flags, int v) {
    int i = threadIdx.x;
    if (i < 256) flags[i * 4] = v;   // per-row flag = completed steps
    if (i == 256) flags[1024] = 0;   // ticket counter
}

// Persistent scan for one 128-step chunk. 1024 blocks launched; 64 workers on
// XCD 0 (ticket-selected), each block = 4 waves = 4 rows. Each WAVE advances
// autonomously: row r at step t needs rows r+{0,±1,±2,±4,±6,±8} of S_{t-1},
// which is exactly the per-row flag set it polls. No intra-block barriers in
// the step loop.
__global__ __launch_bounds__(256) void scan_chunk(
    const float* __restrict__ X,
    const int* __restrict__ perm,
    const float* __restrict__ mc,
    const float* __restrict__ mf,
    float* __restrict__ Sst,      // ping-pong [2][CELLS]
    float* __restrict__ Vsave,    // [CELLS]
    float* __restrict__ Achunk,   // [TB][KTOT]
    int* __restrict__ flags,      // row flags [256*4]; ticket at [1024]
    int t0)
{
#pragma clang fp contract(off)
    __shared__ float4 C5L[4][64];   // per-wave vertical 5-sums  (wave-private)
    __shared__ float4 C9L[4][64];   // per-wave dilated 9-sums   (wave-private)
    __shared__ int sh_b;

    const int tid = threadIdx.x;
    const int xcc = xcc_id();
    if (tid == 0) {
        int tk = -1;
        if (xcc == 0)
            tk = __hip_atomic_fetch_add(&flags[1024], 1, __ATOMIC_RELAXED,
                                        __HIP_MEMORY_SCOPE_AGENT);
        sh_b = tk;
    }
    __syncthreads();
    const int b = sh_b;
    if (b < 0 || b >= NW) return;   // uniform per block

    const int w = tid >> 6;         // wave id = row within strip
    const int l = tid & 63;         // lane = column group (cols 4l..4l+3)
    const int row = b * 4 + w;      // absolute row
    const int cy = row >> 3;        // coarse row

    // step-invariant input-gather state (hoisted out of the t-loop)
    const int cc = cy * 32 + (l >> 1);      // coarse cell for these 4 cols
    const int pidx = perm[cc];
    const float mcv = mc[cc];

    // poll sources: lanes 0..9 poll rows at offsets {±1,±2,±4,±6,±8}
    // (offset 0 is our own row: trivially current)
    const int pi = l % 5;
    const int pmag = (pi == 0) ? 1 : 2 * pi;          // 1,2,4,6,8
    const int po = (l < 5) ? -pmag : pmag;
    const int prow = (row + po) & 255;
    int* pflag = &flags[prow * 4];
    const bool poller = (l < 10);
    volatile int* myf = (volatile int*)&flags[row * 4];

    // V state + fine mask live in registers for the whole chunk.
    float4 V, mfv;
    mfv = *(const float4*)&mf[row * DD + 4 * l];
    if (t0 == 0) V = make_float4(0.f, 0.f, 0.f, 0.f);
    else         V = *(const float4*)&Vsave[row * DD + 4 * l];

    bool bailed = false;
    for (int t = t0; t < t0 + TB; ++t) {
        // 1. wait for source rows to publish S_{t-1}. sc0 loads read L2 directly.
        long g = 0;
        while (__any(poller &&
                     __hip_atomic_load(pflag, __ATOMIC_RELAXED,
                                       __HIP_MEMORY_SCOPE_AGENT) < t)) {
            __builtin_amdgcn_s_sleep(1);
            if (++g > (1L << 22)) { bailed = true; break; }
        }
        if (bailed) {               // unblock dependents, abandon (wrong result,
            if (l == 0) *myf = t0 + TB;   // no hang) — same policy as before
            break;
        }
        // acquire within XCD: drop stale L1 lines; shared L2 is authoritative
        asm volatile("buffer_inv" ::: "memory");

        // 2. input drive for this step (exact: mc in {0,1})
        const float um = tanhf(X[(long)t * 1024 + pidx] * mcv);

        // 3. halo read straight from L2 + vertical sums (exact integer counts)
        const float* Sprev = Sst + (long)((t + 1) & 1) * CELLS;
        float4 s[11];
        if (t > 0) {
            constexpr int DYS[11] = {-8, -6, -4, -2, -1, 0, 1, 2, 4, 6, 8};
#pragma unroll
            for (int i = 0; i < 11; ++i) {
                int gy = (row + DYS[i]) & 255;
                s[i] = *(const float4*)&Sprev[gy * DD + 4 * l];
            }
        } else {
#pragma unroll
            for (int i = 0; i < 11; ++i) s[i] = make_float4(0.f, 0.f, 0.f, 0.f);
        }
        float4 c5 = f4add(f4add(f4add(f4add(s[3], s[4]), s[5]), s[6]), s[7]);
        float4 c9 = f4add(f4add(f4add(f4add(f4add(f4add(f4add(f4add(
                        s[0], s[1]), s[2]), s[3]), s[5]), s[7]), s[8]), s[9]), s[10]);

        // 4. wave-internal column exchange via LDS (in-order DS pipe per wave;
        //    no cross-wave sharing -> no barrier)
        C5L[w][l] = c5;
        C9L[w][l] = c9;
        __builtin_amdgcn_wave_barrier();
        float4 c5m  = C5L[w][(l + 63) & 63];
        float4 c5p  = C5L[w][(l + 1) & 63];
        float4 c9m2 = C9L[w][(l + 62) & 63];
        float4 c9m1 = C9L[w][(l + 63) & 63];
        float4 c9p1 = C9L[w][(l + 1) & 63];
        float4 c9p2 = C9L[w][(l + 2) & 63];

        // 5. horizontal sums + V update (all in registers)
        float e5[8] = {c5m.z, c5m.w, c5.x, c5.y, c5.z, c5.w, c5p.x, c5p.y};
        float e9[20] = {c9m2.x, c9m2.y, c9m2.z, c9m2.w,
                        c9m1.x, c9m1.y, c9m1.z, c9m1.w,
                        c9.x,   c9.y,   c9.z,   c9.w,
                        c9p1.x, c9p1.y, c9p1.z, c9p1.w,
                        c9p2.x, c9p2.y, c9p2.z, c9p2.w};
        float Vc[4]  = {V.x, V.y, V.z, V.w};
        float mfc[4] = {mfv.x, mfv.y, mfv.z, mfv.w};
        float Vn[4], Sn[4];
#pragma unroll
        for (int j = 0; j < 4; ++j) {
            float h5 = e5[j] + e5[j+1] + e5[j+2] + e5[j+3] + e5[j+4];
            float h9 = e9[j] + e9[j+2] + e9[j+4] + e9[j+6] + e9[j+8]
                     + e9[j+10] + e9[j+12] + e9[j+14] + e9[j+16];
            float avg5 = h5 * (1.0f/25.0f);
            float avg9 = h9 * (1.0f/81.0f);
            float lat = avg5 - 0.5f * avg9;          // EXC*avg5 + INH*avg9
            float u = um * mfc[j];                   // exact: mf in {0,1}
            float V1 = 0.9f * Vc[j] + 0.5f * u;      // DECAY*V + SPLIT*x
            float V2 = (V1 >= 0.1f) ? ((V1 + 0.5f * u) + lat) : V1;
            V2 = fminf(V2, 1.0f);
            const bool sp = V2 > 0.75f;
            Vn[j] = sp ? 0.0f : V2;
            Sn[j] = sp ? 1.0f : 0.0f;
        }
        float* Scur = Sst + (long)(t & 1) * CELLS;
        *(float4*)&Scur[row * DD + 4 * l] = make_float4(Sn[0], Sn[1], Sn[2], Sn[3]);

        // 6. release within XCD: drain this wave's stores to write-through L2,
        //    then publish the per-row flag. No block barrier needed.
        asm volatile("s_waitcnt vmcnt(0)" ::: "memory");
        if (l == 0) *myf = t + 1;

        // 7. off-critical-path: readout rows + register rotate
        float* Arow = Achunk + (long)(t - t0) * KTOT;
        *(float4*)&Arow[row * DD + 4 * l] = make_float4(Vn[0], Vn[1], Vn[2], Vn[3]);
        *(float4*)&Arow[CELLS + row * DD + 4 * l] =
            make_float4(Sn[0], Sn[1], Sn[2], Sn[3]);
        V = make_float4(Vn[0], Vn[1], Vn[2], Vn[3]);
    }

    // save V for next chunk
    *(float4*)&Vsave[row * DD + 4 * l] = V;
}

// Split-K fp32 GEMM on one chunk: 64 t x 128 o x KSLAB k per block. Grid (2, NSLAB).
__global__ __launch_bounds__(256) void gemm_partial(
    const float* __restrict__ A,   // chunk [TB][KTOT]
    const float* __restrict__ B,   // W_out [128][KTOT]
    float* __restrict__ P)         // [NSLAB][TB][128]
{
    __shared__ float As[16][68];   // [k][t]
    __shared__ float Bs[16][132];  // [k][o]
    const int tid = threadIdx.x;
    const int t0 = blockIdx.x * 64;
    const long k0 = (long)blockIdx.y * KSLAB;
    const int tx = tid & 15;       // 8 o's each
    const int ty = tid >> 4;       // 4 t's each

    float acc[4][8];
#pragma unroll
    for (int i = 0; i < 4; ++i)
#pragma unroll
        for (int j = 0; j < 8; ++j) acc[i][j] = 0.0f;

    const int ar = tid >> 2, ac = (tid & 3) * 4;   // A: 64 rows x 16 k
    const int br = tid >> 1, bc = (tid & 1) * 8;   // B: 128 rows x 16 k

    for (int kc = 0; kc < KSLAB; kc += 16) {
        float4 av = *(const float4*)&A[(long)(t0 + ar) * KTOT + k0 + kc + ac];
        As[ac+0][ar] = av.x; As[ac+1][ar] = av.y; As[ac+2][ar] = av.z; As[ac+3][ar] = av.w;
        float4 bv0 = *(const float4*)&B[(long)br * KTOT + k0 + kc + bc];
        float4 bv1 = *(const float4*)&B[(long)br * KTOT + k0 + kc + bc + 4];
        Bs[bc+0][br] = bv0.x; Bs[bc+1][br] = bv0.y; Bs[bc+2][br] = bv0.z; Bs[bc+3][br] = bv0.w;
        Bs[bc+4][br] = bv1.x; Bs[bc+5][br] = bv1.y; Bs[bc+6][br] = bv1.z; Bs[bc+7][br] = bv1.w;
        __syncthreads();
#pragma unroll
        for (int kk = 0; kk < 16; ++kk) {
            float4 a4  = *(const float4*)&As[kk][ty*4];
            float4 b40 = *(const float4*)&Bs[kk][tx*8];
            float4 b41 = *(const float4*)&Bs[kk][tx*8+4];
            float a[4] = {a4.x, a4.y, a4.z, a4.w};
            float b[8] = {b40.x, b40.y, b40.z, b40.w, b41.x, b41.y, b41.z, b41.w};
#pragma unroll
            for (int i = 0; i < 4; ++i)
#pragma unroll
                for (int j = 0; j < 8; ++j) acc[i][j] += a[i] * b[j];
        }
        __syncthreads();
    }
#pragma unroll
    for (int i = 0; i < 4; ++i)
#pragma unroll
        for (int j = 0; j < 8; ++j)
            P[((long)blockIdx.y * TB + t0 + ty*4 + i) * 128 + tx*8 + j] = acc[i][j];
}

// Sum NSLAB partials for one chunk, add bias, write out rows [c*TB, (c+1)*TB).
__global__ __launch_bounds__(256) void reduce_kernel(
    const float* __restrict__ P, const float* __restrict__ bias,
    float* __restrict__ out, int c)
{
    int tid = blockIdx.x * 256 + threadIdx.x;      // 16384 = TB*128
    int o = tid & 127;
    float acc = 0.0f;
#pragma unroll 8
    for (int j = 0; j < NSLAB; ++j) acc += P[(long)j * (TB * 128) + tid];
    out[(long)c * (TB * 128) + tid] = acc + bias[o];
}

} // namespace

extern "C" void kernel_launch(void* const* d_in, const int* in_sizes, int n_in,
                              void* d_out, int out_size, void* d_ws, size_t ws_size,
                              hipStream_t stream)
{
    const float* X  = (const float*)d_in[0];   // [512,1024]
    const float* We = (const float*)d_in[1];   // [1024,1024] permuted identity
    const float* mc = (const float*)d_in[2];   // [32,32]
    const float* mf = (const float*)d_in[3];   // [256,256]
    const float* Wo = (const float*)d_in[4];   // [128,2,256,256]
    const float* bo = (const float*)d_in[5];   // [128]
    float* out = (float*)d_out;                // [512,128] fp32

    if (ws_size < (size_t)WS_REQUIRED) return;  // fail loudly (wrong result, no fault)

    char* ws = (char*)d_ws;
    int*   perm   = (int*)(ws + OFF_PERM);
    int*   flags  = (int*)(ws + OFF_FLAG);
    float* Vsave  = (float*)(ws + OFF_VSAVE);
    float* Sst    = (float*)(ws + OFF_S);
    float* Achunk = (float*)(ws + OFF_A);
    float* P      = (float*)(ws + OFF_P);

    perm_kernel<<<4096, 256, 0, stream>>>(We, perm);
    for (int c = 0; c < NCH; ++c) {
        ctrl_init<<<1, 512, 0, stream>>>(flags, c * TB);
        scan_chunk<<<1024, 256, 0, stream>>>(X, perm, mc, mf, Sst, Vsave, Achunk,
                                             flags, c * TB);
        gemm_partial<<<dim3(2, NSLAB), 256, 0, stream>>>(Achunk, Wo, P);
        reduce_kernel<<<64, 256, 0, stream>>>(P, bo, out, c);
    }
}

// Round 2
// 2085.617 us; speedup vs baseline: 1.5555x; 1.5555x over previous
//
#include <hip/hip_runtime.h>
#include <cstdint>

// Cortex reservoir: embed(perm-gather) -> single-XCD persistent neighbor-synced
// spiking scan -> chunked dense readout GEMM.
//
// Scan coherence design (gfx950, 8 XCDs): all 64 worker blocks are confined to
// XCD 0 (HW_REG_XCC_ID + ticket). Within one XCD the L2 is the coherence point:
//   release = s_waitcnt vmcnt(0) (stores reach write-through L2), then plain flag store
//   acquire = volatile flag load with buffer_inv (L1-only invalidate) in the poll loop
// Flags are plain L2-coherent ints (no sc1 / Infinity-Cache round-trips).
//
// R2 hybrid: round-0's verified block-level sync skeleton (flags, 4 pollers,
// 20-row LDS staging, vmcnt(0)+barrier+flag release) + round-1's verified
// float4 wave-per-row compute (11 b128 vertical taps, wave-private C5L/C9L
// horizontal exchange). Cuts per-thread LDS ops ~120 b32 -> ~24 b128 while
// keeping the sync protocol that measured best.
//
// ws layout (~72.8 MiB):
//   OFF_PERM  : perm int[1024]
//   OFF_FLAG  : flags int[64*16] (padded) + ticket at [1024]
//   OFF_VSAVE : V snapshot float[65536]
//   OFF_S     : S ping-pong float[2][65536]
//   OFF_A     : A chunk float[128][131072]
//   OFF_P     : split-K partials float[128][128][128]

namespace {

constexpr int TT = 512;
constexpr int DD = 256;
constexpr int CELLS = DD * DD;              // 65536
constexpr long KTOT = 2L * CELLS;           // 131072
constexpr int TB = 128;                     // time-chunk
constexpr int NCH = TT / TB;                // 4
constexpr int KSLAB = 1024;
constexpr int NSLAB = 128;                  // KTOT / KSLAB
constexpr int NW = 64;                      // worker blocks (one XCD)

constexpr long OFF_PERM = 0;
constexpr long OFF_FLAG = 4096;
constexpr long OFF_VSAVE = OFF_FLAG + 8192;
constexpr long OFF_S = OFF_VSAVE + (long)CELLS * 4;
constexpr long OFF_A = OFF_S + 2L * CELLS * 4;
constexpr long OFF_P = OFF_A + (long)TB * KTOT * 4;
constexpr long WS_REQUIRED = OFF_P + (long)NSLAB * TB * 128 * 4;  // ~72.8 MiB

__device__ __forceinline__ int xcc_id() {
    int x;
    asm volatile("s_getreg_b32 %0, hwreg(HW_REG_XCC_ID, 0, 4)" : "=s"(x));
    return x;
}

__device__ __forceinline__ float4 f4add(float4 a, float4 b) {
    return make_float4(a.x + b.x, a.y + b.y, a.z + b.z, a.w + b.w);
}

__global__ __launch_bounds__(256) void perm_kernel(const float* __restrict__ We,
                                                   int* __restrict__ perm) {
    int idx = blockIdx.x * 256 + threadIdx.x;       // over 1024*1024
    if (We[idx] > 0.5f) perm[idx >> 10] = idx & 1023;
}

__global__ void ctrl_init(int* __restrict__ flags, int v) {
    int i = threadIdx.x;
    if (i < NW) flags[i * 16] = v;
    if (i == NW) flags[1024] = 0;   // ticket counter
}

// Persistent scan for one 128-step chunk. 1024 blocks launched; 64 workers on
// XCD 0 (ticket-selected), each block = 4 waves = 4 rows (wave w owns row
// y0+w; lane l owns cols 4l..4l+3 as float4). Block b at step t needs S_{t-1}
// from blocks b+-1, b+-2 (circular, radius 8 rows = 2 strips).
__global__ __launch_bounds__(256) void scan_chunk(
    const float* __restrict__ X,
    const int* __restrict__ perm,
    const float* __restrict__ mc,
    const float* __restrict__ mf,
    float* __restrict__ Sst,      // ping-pong [2][CELLS]
    float* __restrict__ Vsave,    // [CELLS]
    float* __restrict__ Achunk,   // [TB][KTOT]
    int* __restrict__ flags,      // padded [64*16]; ticket at [1024]
    int t0)
{
#pragma clang fp contract(off)
    __shared__ float Sld[20][DD];   // rows y0-8 .. y0+11 of S_{t-1} (20 KB)
    __shared__ float4 C5L[4][64];   // per-wave vertical 5-sums  (wave-private)
    __shared__ float4 C9L[4][64];   // per-wave dilated 9-sums   (wave-private)
    __shared__ int sh_b;
    __shared__ int sh_bail;

    const int tid = threadIdx.x;
    const int xcc = xcc_id();
    if (tid == 0) {
        int tk = -1;
        if (xcc == 0)
            tk = __hip_atomic_fetch_add(&flags[1024], 1, __ATOMIC_RELAXED,
                                        __HIP_MEMORY_SCOPE_AGENT);
        sh_b = tk;
        sh_bail = 0;
    }
    __syncthreads();
    const int b = sh_b;
    if (b < 0 || b >= NW) return;   // uniform per block

    const int y0 = b * 4;           // 4-row strip, inside one coarse row
    const int w = tid >> 6;         // wave id = row within strip
    const int l = tid & 63;         // lane = column group (cols 4l..4l+3)
    const int row = y0 + w;         // absolute row
    const int cy = row >> 3;        // coarse row (strip is inside one)

    // step-invariant input-gather state (hoisted out of the t-loop)
    const int cc = cy * 32 + (l >> 1);      // coarse cell for these 4 cols
    const int pidx = perm[cc];
    const float mcv = mc[cc];

    // neighbor flag slot for this polling thread (tid 0..3, i.e. wave 0)
    const int nbi = (tid == 0) ? ((b + 62) & 63) : (tid == 1) ? ((b + 63) & 63)
                  : (tid == 2) ? ((b + 1) & 63)  : ((b + 2) & 63);
    volatile int* nbf = (volatile int*)&flags[nbi * 16];
    volatile int* myf = (volatile int*)&flags[b * 16];

    // V state + fine mask live in registers for the whole chunk.
    float4 V, mfv;
    mfv = *(const float4*)&mf[row * DD + 4 * l];
    if (t0 == 0) V = make_float4(0.f, 0.f, 0.f, 0.f);
    else         V = *(const float4*)&Vsave[row * DD + 4 * l];

    for (int t = t0; t < t0 + TB; ++t) {
        // 1. wait for neighbors to publish S_{t-1} (flag == completed steps).
        //    Threads 0..3 poll one neighbor each, in parallel, at L2.
        if (tid < 4) {
            long g = 0;
            while (*nbf < t) {
                asm volatile("buffer_inv" ::: "memory");  // drop stale L1 lines
                if (++g > (1L << 22)) { sh_bail = 1; break; }
            }
        }
        __syncthreads();
        if (sh_bail) {              // let neighbors terminate too, then abandon
            if (tid == 0) *myf = t0 + TB;
            break;
        }
        // acquire within XCD: drop stale L1 lines; shared L2 is authoritative
        asm volatile("buffer_inv" ::: "memory");

        // 2. input drive for this step (exact: mc in {0,1})
        const float um = tanhf(X[(long)t * 1024 + pidx] * mcv);

        // 3. halo load: 20 rows of S_{t-1} (slot (t+1)&1)
        const float* Sprev = Sst + (long)((t + 1) & 1) * CELLS;
        for (int i = tid; i < 20 * 64; i += 256) {
            int rr = i >> 6;
            int x4 = (i & 63) << 2;
            float4 s4 = make_float4(0.f, 0.f, 0.f, 0.f);
            if (t > 0) {
                int gy = (y0 - 8 + rr) & 255;
                s4 = *(const float4*)&Sprev[gy * DD + x4];
            }
            *(float4*)&Sld[rr][x4] = s4;
        }
        __syncthreads();

        // 4. vertical taps from Sld, float4 per lane (exact integer counts).
        //    Own row sits at rr = w+8; taps span rr-8..rr+8 within [0,20).
        float4 s[11];
        {
            constexpr int DYS[11] = {-8, -6, -4, -2, -1, 0, 1, 2, 4, 6, 8};
#pragma unroll
            for (int i = 0; i < 11; ++i)
                s[i] = *(const float4*)&Sld[w + 8 + DYS[i]][4 * l];
        }
        float4 c5 = f4add(f4add(f4add(f4add(s[3], s[4]), s[5]), s[6]), s[7]);
        float4 c9 = f4add(f4add(f4add(f4add(f4add(f4add(f4add(f4add(
                        s[0], s[1]), s[2]), s[3]), s[5]), s[7]), s[8]), s[9]), s[10]);

        // 5. wave-internal column exchange via LDS (in-order DS pipe per wave;
        //    wave-private buffers -> only wave_barrier needed)
        C5L[w][l] = c5;
        C9L[w][l] = c9;
        __builtin_amdgcn_wave_barrier();
        float4 c5m  = C5L[w][(l + 63) & 63];
        float4 c5p  = C5L[w][(l + 1) & 63];
        float4 c9m2 = C9L[w][(l + 62) & 63];
        float4 c9m1 = C9L[w][(l + 63) & 63];
        float4 c9p1 = C9L[w][(l + 1) & 63];
        float4 c9p2 = C9L[w][(l + 2) & 63];
        __builtin_amdgcn_wave_barrier();

        // 6. horizontal sums + V update (all in registers)
        float e5[8] = {c5m.z, c5m.w, c5.x, c5.y, c5.z, c5.w, c5p.x, c5p.y};
        float e9[20] = {c9m2.x, c9m2.y, c9m2.z, c9m2.w,
                        c9m1.x, c9m1.y, c9m1.z, c9m1.w,
                        c9.x,   c9.y,   c9.z,   c9.w,
                        c9p1.x, c9p1.y, c9p1.z, c9p1.w,
                        c9p2.x, c9p2.y, c9p2.z, c9p2.w};
        float Vc[4]  = {V.x, V.y, V.z, V.w};
        float mfc[4] = {mfv.x, mfv.y, mfv.z, mfv.w};
        float Vn[4], Sn[4];
#pragma unroll
        for (int j = 0; j < 4; ++j) {
            float h5 = e5[j] + e5[j+1] + e5[j+2] + e5[j+3] + e5[j+4];
            float h9 = e9[j] + e9[j+2] + e9[j+4] + e9[j+6] + e9[j+8]
                     + e9[j+10] + e9[j+12] + e9[j+14] + e9[j+16];
            float avg5 = h5 * (1.0f/25.0f);
            float avg9 = h9 * (1.0f/81.0f);
            float lat = avg5 - 0.5f * avg9;          // EXC*avg5 + INH*avg9
            float u = um * mfc[j];                   // exact: mf in {0,1}
            float V1 = 0.9f * Vc[j] + 0.5f * u;      // DECAY*V + SPLIT*x
            float V2 = (V1 >= 0.1f) ? ((V1 + 0.5f * u) + lat) : V1;
            V2 = fminf(V2, 1.0f);
            const bool sp = V2 > 0.75f;
            Vn[j] = sp ? 0.0f : V2;
            Sn[j] = sp ? 1.0f : 0.0f;
        }
        float* Scur = Sst + (long)(t & 1) * CELLS;
        *(float4*)&Scur[row * DD + 4 * l] = make_float4(Sn[0], Sn[1], Sn[2], Sn[3]);

        // 7. release within XCD: drain own stores to the write-through L2, flag.
        asm volatile("s_waitcnt vmcnt(0)" ::: "memory");
        __syncthreads();                 // all waves drained
        if (tid == 0) *myf = t + 1;      // plain store -> L2 (flag slot)

        // 8. off-critical-path: readout rows + register rotate
        float* Arow = Achunk + (long)(t - t0) * KTOT;
        *(float4*)&Arow[row * DD + 4 * l] = make_float4(Vn[0], Vn[1], Vn[2], Vn[3]);
        *(float4*)&Arow[CELLS + row * DD + 4 * l] =
            make_float4(Sn[0], Sn[1], Sn[2], Sn[3]);
        V = make_float4(Vn[0], Vn[1], Vn[2], Vn[3]);
    }

    // save V for next chunk
    *(float4*)&Vsave[row * DD + 4 * l] = V;
}

// Split-K fp32 GEMM on one chunk: 64 t x 128 o x KSLAB k per block. Grid (2, NSLAB).
__global__ __launch_bounds__(256) void gemm_partial(
    const float* __restrict__ A,   // chunk [TB][KTOT]
    const float* __restrict__ B,   // W_out [128][KTOT]
    float* __restrict__ P)         // [NSLAB][TB][128]
{
    __shared__ float As[16][68];   // [k][t]
    __shared__ float Bs[16][132];  // [k][o]
    const int tid = threadIdx.x;
    const int t0 = blockIdx.x * 64;
    const long k0 = (long)blockIdx.y * KSLAB;
    const int tx = tid & 15;       // 8 o's each
    const int ty = tid >> 4;       // 4 t's each

    float acc[4][8];
#pragma unroll
    for (int i = 0; i < 4; ++i)
#pragma unroll
        for (int j = 0; j < 8; ++j) acc[i][j] = 0.0f;

    const int ar = tid >> 2, ac = (tid & 3) * 4;   // A: 64 rows x 16 k
    const int br = tid >> 1, bc = (tid & 1) * 8;   // B: 128 rows x 16 k

    for (int kc = 0; kc < KSLAB; kc += 16) {
        float4 av = *(const float4*)&A[(long)(t0 + ar) * KTOT + k0 + kc + ac];
        As[ac+0][ar] = av.x; As[ac+1][ar] = av.y; As[ac+2][ar] = av.z; As[ac+3][ar] = av.w;
        float4 bv0 = *(const float4*)&B[(long)br * KTOT + k0 + kc + bc];
        float4 bv1 = *(const float4*)&B[(long)br * KTOT + k0 + kc + bc + 4];
        Bs[bc+0][br] = bv0.x; Bs[bc+1][br] = bv0.y; Bs[bc+2][br] = bv0.z; Bs[bc+3][br] = bv0.w;
        Bs[bc+4][br] = bv1.x; Bs[bc+5][br] = bv1.y; Bs[bc+6][br] = bv1.z; Bs[bc+7][br] = bv1.w;
        __syncthreads();
#pragma unroll
        for (int kk = 0; kk < 16; ++kk) {
            float4 a4  = *(const float4*)&As[kk][ty*4];
            float4 b40 = *(const float4*)&Bs[kk][tx*8];
            float4 b41 = *(const float4*)&Bs[kk][tx*8+4];
            float a[4] = {a4.x, a4.y, a4.z, a4.w};
            float b[8] = {b40.x, b40.y, b40.z, b40.w, b41.x, b41.y, b41.z, b41.w};
#pragma unroll
            for (int i = 0; i < 4; ++i)
#pragma unroll
                for (int j = 0; j < 8; ++j) acc[i][j] += a[i] * b[j];
        }
        __syncthreads();
    }
#pragma unroll
    for (int i = 0; i < 4; ++i)
#pragma unroll
        for (int j = 0; j < 8; ++j)
            P[((long)blockIdx.y * TB + t0 + ty*4 + i) * 128 + tx*8 + j] = acc[i][j];
}

// Sum NSLAB partials for one chunk, add bias, write out rows [c*TB, (c+1)*TB).
__global__ __launch_bounds__(256) void reduce_kernel(
    const float* __restrict__ P, const float* __restrict__ bias,
    float* __restrict__ out, int c)
{
    int tid = blockIdx.x * 256 + threadIdx.x;      // 16384 = TB*128
    int o = tid & 127;
    float acc = 0.0f;
#pragma unroll 8
    for (int j = 0; j < NSLAB; ++j) acc += P[(long)j * (TB * 128) + tid];
    out[(long)c * (TB * 128) + tid] = acc + bias[o];
}

} // namespace

extern "C" void kernel_launch(void* const* d_in, const int* in_sizes, int n_in,
                              void* d_out, int out_size, void* d_ws, size_t ws_size,
                              hipStream_t stream)
{
    const float* X  = (const float*)d_in[0];   // [512,1024]
    const float* We = (const float*)d_in[1];   // [1024,1024] permuted identity
    const float* mc = (const float*)d_in[2];   // [32,32]
    const float* mf = (const float*)d_in[3];   // [256,256]
    const float* Wo = (const float*)d_in[4];   // [128,2,256,256]
    const float* bo = (const float*)d_in[5];   // [128]
    float* out = (float*)d_out;                // [512,128] fp32

    if (ws_size < (size_t)WS_REQUIRED) return;  // fail loudly (wrong result, no fault)

    char* ws = (char*)d_ws;
    int*   perm   = (int*)(ws + OFF_PERM);
    int*   flags  = (int*)(ws + OFF_FLAG);
    float* Vsave  = (float*)(ws + OFF_VSAVE);
    float* Sst    = (float*)(ws + OFF_S);
    float* Achunk = (float*)(ws + OFF_A);
    float* P      = (float*)(ws + OFF_P);

    perm_kernel<<<4096, 256, 0, stream>>>(We, perm);
    for (int c = 0; c < NCH; ++c) {
        ctrl_init<<<1, 128, 0, stream>>>(flags, c * TB);
        scan_chunk<<<1024, 256, 0, stream>>>(X, perm, mc, mf, Sst, Vsave, Achunk,
                                             flags, c * TB);
        gemm_partial<<<dim3(2, NSLAB), 256, 0, stream>>>(Achunk, Wo, P);
        reduce_kernel<<<64, 256, 0, stream>>>(P, bo, out, c);
    }
}

// Round 3
// 1904.365 us; speedup vs baseline: 1.7035x; 1.0952x over previous
//
#include <hip/hip_runtime.h>
#include <cstdint>

// Cortex reservoir: embed(perm-gather) -> single-XCD persistent wave-autonomous
// spiking scan (tagged-data sync) -> chunked dense readout GEMM.
//
// R3 scan sync: S is binary, so each lane's 4 cells pack into ONE dword:
//   pk = S0 | S1<<4 | S2<<8 | S3<<12 | (t+1)<<16     (nibbles + step tag)
// The publisher's plain store of pk IS the publication (write-through L1 ->
// XCD-0 L2). Consumers poll their 10 tap dwords with agent-scope (sc0,
// L1-bypass) loads until all tags match t. This merges {vmcnt(0) drain,
// __syncthreads, flag store, flag poll+buffer_inv, separate halo load} into
// ONE L2 round trip. Tap set {+-1,+-2,+-4,+-6,+-8} is symmetric -> any reader
// of row p is a tap of p -> p never overwrites a buffer a reader still needs
// (2-buffer ping-pong race-free). Vertical sums run in the nibble-int domain
// (counts <= 9 < 16, carry-free), then convert to float -> bit-identical to
// the verified round-2 float math.
//
// ws layout:
//   OFF_PERM  : perm int[1024]
//   OFF_FLAG  : ticket at int[1024]
//   OFF_VSAVE : V snapshot float[65536]
//   OFF_S     : Spub packed ping-pong uint[2][256][64] (128 KiB of 512 KiB slot)
//   OFF_A     : A chunk float[128][131072]
//   OFF_P     : split-K partials float[128][128][128]

namespace {

constexpr int TT = 512;
constexpr int DD = 256;
constexpr int CELLS = DD * DD;              // 65536
constexpr long KTOT = 2L * CELLS;           // 131072
constexpr int TB = 128;                     // time-chunk
constexpr int NCH = TT / TB;                // 4
constexpr int KSLAB = 1024;
constexpr int NSLAB = 128;                  // KTOT / KSLAB
constexpr int NW = 64;                      // worker blocks (one XCD)

constexpr long OFF_PERM = 0;
constexpr long OFF_FLAG = 4096;
constexpr long OFF_VSAVE = OFF_FLAG + 8192;
constexpr long OFF_S = OFF_VSAVE + (long)CELLS * 4;
constexpr long OFF_A = OFF_S + 2L * CELLS * 4;
constexpr long OFF_P = OFF_A + (long)TB * KTOT * 4;
constexpr long WS_REQUIRED = OFF_P + (long)NSLAB * TB * 128 * 4;  // ~72.8 MiB

__device__ __forceinline__ int xcc_id() {
    int x;
    asm volatile("s_getreg_b32 %0, hwreg(HW_REG_XCC_ID, 0, 4)" : "=s"(x));
    return x;
}

__global__ __launch_bounds__(256) void perm_kernel(const float* __restrict__ We,
                                                   int* __restrict__ perm) {
    int idx = blockIdx.x * 256 + threadIdx.x;       // over 1024*1024
    if (We[idx] > 0.5f) perm[idx >> 10] = idx & 1023;
}

// Reset ticket; zero the packed-S buffers at t0==0 (kills stale tags across
// graph replays / workspace re-poison).
__global__ void ctrl_init(int* __restrict__ flags, unsigned int* __restrict__ Spub,
                          int zero_spub) {
    int i = blockIdx.x * 256 + threadIdx.x;
    if (i == 0) flags[1024] = 0;                    // ticket counter
    if (zero_spub && i < (1 << 14)) {
        Spub[i] = 0u;
        Spub[i + (1 << 14)] = 0u;
    }
}

// Persistent scan for one 128-step chunk. 1024 blocks launched; 64 workers on
// XCD 0 (ticket-selected), each block = 4 waves = 4 rows (wave w owns row
// b*4+w; lane l owns cols 4l..4l+3). Each WAVE advances autonomously: no
// barriers, no flags — it polls the tagged packed-S dwords of its 10 tap rows.
__global__ __launch_bounds__(256) void scan_chunk(
    const float* __restrict__ X,
    const int* __restrict__ perm,
    const float* __restrict__ mc,
    const float* __restrict__ mf,
    unsigned int* __restrict__ Spub,   // packed ping-pong [2][256][64]
    float* __restrict__ Vsave,         // [CELLS]
    float* __restrict__ Achunk,        // [TB][KTOT]
    int* __restrict__ flags,           // ticket at [1024]
    int t0)
{
#pragma clang fp contract(off)
    __shared__ float4 C5L[4][64];   // per-wave vertical 5-sums  (wave-private)
    __shared__ float4 C9L[4][64];   // per-wave dilated 9-sums   (wave-private)
    __shared__ int sh_b;

    const int tid = threadIdx.x;
    if (tid == 0) {
        int tk = -1;
        if (xcc_id() == 0)
            tk = __hip_atomic_fetch_add(&flags[1024], 1, __ATOMIC_RELAXED,
                                        __HIP_MEMORY_SCOPE_AGENT);
        sh_b = tk;
    }
    __syncthreads();
    const int b = sh_b;
    if (b < 0 || b >= NW) return;   // uniform per block

    const int w = tid >> 6;         // wave id = row within strip
    const int l = tid & 63;         // lane = column group (cols 4l..4l+3)
    const int row = b * 4 + w;      // absolute row
    const int cy = row >> 3;        // coarse row

    // step-invariant input-gather state
    const int cc = cy * 32 + (l >> 1);
    const int pidx = perm[cc];
    const float mcv = mc[cc];

    // tap row offsets into a packed buffer (own row stays in registers)
    constexpr int DYS10[10] = {-8, -6, -4, -2, -1, 1, 2, 4, 6, 8};
    int toff[10];
#pragma unroll
    for (int i = 0; i < 10; ++i)
        toff[i] = (((row + DYS10[i]) & 255) << 6) | l;

    // V state + fine mask + own packed S live in registers for the chunk.
    float4 V;
    const float4 mfv = *(const float4*)&mf[row * DD + 4 * l];
    unsigned int own;               // own S as 4 nibbles (low 16 bits)
    if (t0 == 0) {
        V = make_float4(0.f, 0.f, 0.f, 0.f);
        own = 0u;
    } else {
        V = *(const float4*)&Vsave[row * DD + 4 * l];
        // published at end of step t0-1 into buf[(t0-1)&1] == buf[(t0+1)&1];
        // prior kernel completion makes it visible (launch-boundary acquire).
        own = Spub[(((t0 + 1) & 1) << 14) + (row << 6) + l] & 0xFFFFu;
    }

    for (int t = t0; t < t0 + TB; ++t) {
        // 1. acquire S_{t-1} taps: poll tagged dwords straight from L2 (sc0).
        unsigned int tp[10];
        if (t > 0) {
            const unsigned int* base = Spub + (((t + 1) & 1) << 14);
            const unsigned int tag = (unsigned int)t;
            long g = 0;
            bool ok;
            do {
#pragma unroll
                for (int i = 0; i < 10; ++i)
                    tp[i] = __hip_atomic_load(&base[toff[i]], __ATOMIC_RELAXED,
                                              __HIP_MEMORY_SCOPE_AGENT);
                bool mine = true;
#pragma unroll
                for (int i = 0; i < 10; ++i) mine &= ((tp[i] >> 16) == tag);
                ok = __all(mine);
                if (++g > (1L << 18)) break;
            } while (!ok);
            if (!ok) break;   // bail: wrong result, no hang (others bail too)
#pragma unroll
            for (int i = 0; i < 10; ++i) tp[i] &= 0xFFFFu;
        } else {
#pragma unroll
            for (int i = 0; i < 10; ++i) tp[i] = 0u;
        }

        // 2. input drive (exact: mc in {0,1})
        const float um = tanhf(X[(long)t * 1024 + pidx] * mcv);

        // 3. vertical sums in nibble-int domain (counts <= 9 < 16, no carry),
        //    then convert -> floats identical to the verified float path.
        const unsigned int c5i = tp[3] + tp[4] + own + tp[5] + tp[6];
        const unsigned int c9i = tp[0] + tp[1] + tp[2] + tp[3] + own
                               + tp[6] + tp[7] + tp[8] + tp[9];
        float4 c5 = make_float4((float)(c5i & 0xFu), (float)((c5i >> 4) & 0xFu),
                                (float)((c5i >> 8) & 0xFu), (float)((c5i >> 12) & 0xFu));
        float4 c9 = make_float4((float)(c9i & 0xFu), (float)((c9i >> 4) & 0xFu),
                                (float)((c9i >> 8) & 0xFu), (float)((c9i >> 12) & 0xFu));

        // 4. wave-internal column exchange via LDS (wave-private -> no barrier)
        C5L[w][l] = c5;
        C9L[w][l] = c9;
        __builtin_amdgcn_wave_barrier();
        float4 c5m  = C5L[w][(l + 63) & 63];
        float4 c5p  = C5L[w][(l + 1) & 63];
        float4 c9m2 = C9L[w][(l + 62) & 63];
        float4 c9m1 = C9L[w][(l + 63) & 63];
        float4 c9p1 = C9L[w][(l + 1) & 63];
        float4 c9p2 = C9L[w][(l + 2) & 63];
        __builtin_amdgcn_wave_barrier();

        // 5. horizontal sums + V update (all in registers; verbatim round-2)
        float e5[8] = {c5m.z, c5m.w, c5.x, c5.y, c5.z, c5.w, c5p.x, c5p.y};
        float e9[20] = {c9m2.x, c9m2.y, c9m2.z, c9m2.w,
                        c9m1.x, c9m1.y, c9m1.z, c9m1.w,
                        c9.x,   c9.y,   c9.z,   c9.w,
                        c9p1.x, c9p1.y, c9p1.z, c9p1.w,
                        c9p2.x, c9p2.y, c9p2.z, c9p2.w};
        float Vc[4]  = {V.x, V.y, V.z, V.w};
        float mfc[4] = {mfv.x, mfv.y, mfv.z, mfv.w};
        float Vn[4], Sn[4];
        unsigned int ipk = 0;
#pragma unroll
        for (int j = 0; j < 4; ++j) {
            float h5 = e5[j] + e5[j+1] + e5[j+2] + e5[j+3] + e5[j+4];
            float h9 = e9[j] + e9[j+2] + e9[j+4] + e9[j+6] + e9[j+8]
                     + e9[j+10] + e9[j+12] + e9[j+14] + e9[j+16];
            float avg5 = h5 * (1.0f/25.0f);
            float avg9 = h9 * (1.0f/81.0f);
            float lat = avg5 - 0.5f * avg9;          // EXC*avg5 + INH*avg9
            float u = um * mfc[j];                   // exact: mf in {0,1}
            float V1 = 0.9f * Vc[j] + 0.5f * u;      // DECAY*V + SPLIT*x
            float V2 = (V1 >= 0.1f) ? ((V1 + 0.5f * u) + lat) : V1;
            V2 = fminf(V2, 1.0f);
            const bool sp = V2 > 0.75f;
            Vn[j] = sp ? 0.0f : V2;
            Sn[j] = sp ? 1.0f : 0.0f;
            if (sp) ipk |= 1u << (4 * j);
        }

        // 6. publish: the tagged packed store IS the release (L2 write-through).
        __hip_atomic_store(&Spub[((t & 1) << 14) + (row << 6) + l],
                           ipk | ((unsigned int)(t + 1) << 16),
                           __ATOMIC_RELAXED, __HIP_MEMORY_SCOPE_AGENT);
        own = ipk;

        // 7. off-critical-path: readout rows + register rotate
        float* Arow = Achunk + (long)(t - t0) * KTOT;
        *(float4*)&Arow[row * DD + 4 * l] = make_float4(Vn[0], Vn[1], Vn[2], Vn[3]);
        *(float4*)&Arow[CELLS + row * DD + 4 * l] =
            make_float4(Sn[0], Sn[1], Sn[2], Sn[3]);
        V = make_float4(Vn[0], Vn[1], Vn[2], Vn[3]);
    }

    // save V for next chunk
    *(float4*)&Vsave[row * DD + 4 * l] = V;
}

// Split-K fp32 GEMM on one chunk: 64 t x 128 o x KSLAB k per block. Grid (2, NSLAB).
__global__ __launch_bounds__(256) void gemm_partial(
    const float* __restrict__ A,   // chunk [TB][KTOT]
    const float* __restrict__ B,   // W_out [128][KTOT]
    float* __restrict__ P)         // [NSLAB][TB][128]
{
    __shared__ float As[16][68];   // [k][t]
    __shared__ float Bs[16][132];  // [k][o]
    const int tid = threadIdx.x;
    const int t0 = blockIdx.x * 64;
    const long k0 = (long)blockIdx.y * KSLAB;
    const int tx = tid & 15;       // 8 o's each
    const int ty = tid >> 4;       // 4 t's each

    float acc[4][8];
#pragma unroll
    for (int i = 0; i < 4; ++i)
#pragma unroll
        for (int j = 0; j < 8; ++j) acc[i][j] = 0.0f;

    const int ar = tid >> 2, ac = (tid & 3) * 4;   // A: 64 rows x 16 k
    const int br = tid >> 1, bc = (tid & 1) * 8;   // B: 128 rows x 16 k

    for (int kc = 0; kc < KSLAB; kc += 16) {
        float4 av = *(const float4*)&A[(long)(t0 + ar) * KTOT + k0 + kc + ac];
        As[ac+0][ar] = av.x; As[ac+1][ar] = av.y; As[ac+2][ar] = av.z; As[ac+3][ar] = av.w;
        float4 bv0 = *(const float4*)&B[(long)br * KTOT + k0 + kc + bc];
        float4 bv1 = *(const float4*)&B[(long)br * KTOT + k0 + kc + bc + 4];
        Bs[bc+0][br] = bv0.x; Bs[bc+1][br] = bv0.y; Bs[bc+2][br] = bv0.z; Bs[bc+3][br] = bv0.w;
        Bs[bc+4][br] = bv1.x; Bs[bc+5][br] = bv1.y; Bs[bc+6][br] = bv1.z; Bs[bc+7][br] = bv1.w;
        __syncthreads();
#pragma unroll
        for (int kk = 0; kk < 16; ++kk) {
            float4 a4  = *(const float4*)&As[kk][ty*4];
            float4 b40 = *(const float4*)&Bs[kk][tx*8];
            float4 b41 = *(const float4*)&Bs[kk][tx*8+4];
            float a[4] = {a4.x, a4.y, a4.z, a4.w};
            float b[8] = {b40.x, b40.y, b40.z, b40.w, b41.x, b41.y, b41.z, b41.w};
#pragma unroll
            for (int i = 0; i < 4; ++i)
#pragma unroll
                for (int j = 0; j < 8; ++j) acc[i][j] += a[i] * b[j];
        }
        __syncthreads();
    }
#pragma unroll
    for (int i = 0; i < 4; ++i)
#pragma unroll
        for (int j = 0; j < 8; ++j)
            P[((long)blockIdx.y * TB + t0 + ty*4 + i) * 128 + tx*8 + j] = acc[i][j];
}

// Sum NSLAB partials for one chunk, add bias, write out rows [c*TB, (c+1)*TB).
__global__ __launch_bounds__(256) void reduce_kernel(
    const float* __restrict__ P, const float* __restrict__ bias,
    float* __restrict__ out, int c)
{
    int tid = blockIdx.x * 256 + threadIdx.x;      // 16384 = TB*128
    int o = tid & 127;
    float acc = 0.0f;
#pragma unroll 8
    for (int j = 0; j < NSLAB; ++j) acc += P[(long)j * (TB * 128) + tid];
    out[(long)c * (TB * 128) + tid] = acc + bias[o];
}

} // namespace

extern "C" void kernel_launch(void* const* d_in, const int* in_sizes, int n_in,
                              void* d_out, int out_size, void* d_ws, size_t ws_size,
                              hipStream_t stream)
{
    const float* X  = (const float*)d_in[0];   // [512,1024]
    const float* We = (const float*)d_in[1];   // [1024,1024] permuted identity
    const float* mc = (const float*)d_in[2];   // [32,32]
    const float* mf = (const float*)d_in[3];   // [256,256]
    const float* Wo = (const float*)d_in[4];   // [128,2,256,256]
    const float* bo = (const float*)d_in[5];   // [128]
    float* out = (float*)d_out;                // [512,128] fp32

    if (ws_size < (size_t)WS_REQUIRED) return;  // fail loudly (wrong result, no fault)

    char* ws = (char*)d_ws;
    int*          perm   = (int*)(ws + OFF_PERM);
    int*          flags  = (int*)(ws + OFF_FLAG);
    float*        Vsave  = (float*)(ws + OFF_VSAVE);
    unsigned int* Spub   = (unsigned int*)(ws + OFF_S);
    float*        Achunk = (float*)(ws + OFF_A);
    float*        P      = (float*)(ws + OFF_P);

    perm_kernel<<<4096, 256, 0, stream>>>(We, perm);
    for (int c = 0; c < NCH; ++c) {
        ctrl_init<<<64, 256, 0, stream>>>(flags, Spub, c == 0 ? 1 : 0);
        scan_chunk<<<1024, 256, 0, stream>>>(X, perm, mc, mf, Spub, Vsave, Achunk,
                                             flags, c * TB);
        gemm_partial<<<dim3(2, NSLAB), 256, 0, stream>>>(Achunk, Wo, P);
        reduce_kernel<<<64, 256, 0, stream>>>(P, bo, out, c);
    }
}